// Round 5
// baseline (162.574 us; speedup 1.0000x reference)
//
#include <hip/hip_runtime.h>
#include <hip/hip_bf16.h>

#define B_    4
#define N_    16384
#define D_    128
#define P_    100
#define BN_   65536      // B_*N_
#define PBN_  6553600    // P_*BN_
#define PPAD  112        // P padded to 7*16 MFMA p-tiles (k_proj)
#define KPAD  128        // P padded to 128 for k_comb's K dimension
#define NBIN  4096

typedef __attribute__((ext_vector_type(8))) short short8;   // 8 bf16 = 4 VGPR
typedef __attribute__((ext_vector_type(4))) float floatx4;  // MFMA C/D

// bf16 <-> f32 via raw bits (RNE; inputs are finite)
__device__ __forceinline__ unsigned short f2b(float f) {
    unsigned u = __float_as_uint(f);
    return (unsigned short)((u + 0x7FFFu + ((u >> 16) & 1u)) >> 16);
}
__device__ __forceinline__ float b2f(unsigned short h) {
    return __uint_as_float(((unsigned)h) << 16);
}

// ---------------------------------------------------------------------------
// Kernel 1: theta normalization -> thb[p][d] (k_proj A-operand, rows >=100
// zero) and thbT[d][p] (k_comb B-operand, cols >=100 zero; NaN-safe K-pad).
// ---------------------------------------------------------------------------
__global__ void k_norm(const float* __restrict__ th,
                       unsigned short* __restrict__ thb,
                       unsigned short* __restrict__ thbT) {
    int p = blockIdx.x;       // 0..127
    int d = threadIdx.x;      // 0..127
    float v = 0.f;
    if (p < P_) v = th[p * D_ + d];
    float s = v * v;
    #pragma unroll
    for (int o = 32; o > 0; o >>= 1) s += __shfl_down(s, o, 64);
    __shared__ float red[2];
    if ((d & 63) == 0) red[d >> 6] = s;
    __syncthreads();
    float norm = fmaxf(sqrtf(red[0] + red[1]), 1e-12f);
    unsigned short r = f2b(v / norm);       // p>=100 -> 0/1e-12 = +0
    if (p < PPAD) thb[p * D_ + d] = r;
    thbT[d * KPAD + p] = r;
}

// ---------------------------------------------------------------------------
// Kernel 2: projections via bf16 MFMA 16x16x32.
// R4 fix (Common-mistake #7): theta (28 KB) is L2-resident and re-read by
// every block — do NOT stage it in LDS.  A-fragments load straight from
// global (guaranteed L2 hits, hidden at 16 waves/CU).  LDS keeps only the
// output-coalescing buffers (32.3 KB) -> launch_bounds(256,4): 4 blocks/CU,
// 16 waves/CU (was 2 blocks / 8 waves — 2 waves/SIMD couldn't hide the
// 256 B/thread load phase).  ONE barrier total.
// ---------------------------------------------------------------------------
__global__ __launch_bounds__(256, 4) void k_proj(
    const float* __restrict__ x, const float* __restrict__ y,
    const unsigned short* __restrict__ thb,
    unsigned short* __restrict__ xp, unsigned short* __restrict__ yp) {
    __shared__ unsigned short bufx[8064];     // [112][72]  16,128 B
    __shared__ unsigned short bufy[8064];     // [112][72]  16,128 B
    const int tid  = threadIdx.x;
    const int w    = tid >> 6;                // wave 0..3 -> rows w*16..+15
    const int lane = tid & 63;
    const int n    = lane & 15;
    const int quad = lane >> 4;
    const int row0 = blockIdx.x * 64;

    // x first: 8 float4 loads -> convert; then y (keeps f32 liveness <= 8x4)
    const float* xr = x + (size_t)(row0 + w * 16 + n) * D_ + quad * 8;
    const float* yr = y + (size_t)(row0 + w * 16 + n) * D_ + quad * 8;
    short8 bx[4], by[4];
    {
        float4 lx[8];
        #pragma unroll
        for (int ks = 0; ks < 4; ++ks) {
            lx[2*ks]   = *(const float4*)(xr + ks * 32);
            lx[2*ks+1] = *(const float4*)(xr + ks * 32 + 4);
        }
        #pragma unroll
        for (int ks = 0; ks < 4; ++ks) {
            short8 t;
            t[0] = (short)f2b(lx[2*ks].x);   t[1] = (short)f2b(lx[2*ks].y);
            t[2] = (short)f2b(lx[2*ks].z);   t[3] = (short)f2b(lx[2*ks].w);
            t[4] = (short)f2b(lx[2*ks+1].x); t[5] = (short)f2b(lx[2*ks+1].y);
            t[6] = (short)f2b(lx[2*ks+1].z); t[7] = (short)f2b(lx[2*ks+1].w);
            bx[ks] = t;
        }
    }
    {
        float4 ly[8];
        #pragma unroll
        for (int ks = 0; ks < 4; ++ks) {
            ly[2*ks]   = *(const float4*)(yr + ks * 32);
            ly[2*ks+1] = *(const float4*)(yr + ks * 32 + 4);
        }
        #pragma unroll
        for (int ks = 0; ks < 4; ++ks) {
            short8 t;
            t[0] = (short)f2b(ly[2*ks].x);   t[1] = (short)f2b(ly[2*ks].y);
            t[2] = (short)f2b(ly[2*ks].z);   t[3] = (short)f2b(ly[2*ks].w);
            t[4] = (short)f2b(ly[2*ks+1].x); t[5] = (short)f2b(ly[2*ks+1].y);
            t[6] = (short)f2b(ly[2*ks+1].z); t[7] = (short)f2b(ly[2*ks+1].w);
            by[ks] = t;
        }
    }

    // MFMA loop; A-fragments direct from global thb (L2-resident 28 KB)
    #pragma unroll
    for (int pt = 0; pt < 7; ++pt) {
        floatx4 accx = {0.f, 0.f, 0.f, 0.f};
        floatx4 accy = {0.f, 0.f, 0.f, 0.f};
        #pragma unroll
        for (int ks = 0; ks < 4; ++ks) {
            short8 a = *(const short8*)(thb + (pt * 16 + n) * D_ + ks * 32 + quad * 8);
            accx = __builtin_amdgcn_mfma_f32_16x16x32_bf16(a, bx[ks], accx, 0, 0, 0);
            accy = __builtin_amdgcn_mfma_f32_16x16x32_bf16(a, by[ks], accy, 0, 0, 0);
        }
        #pragma unroll
        for (int reg = 0; reg < 4; ++reg) {
            int p = pt * 16 + quad * 4 + reg;
            bufx[p * 72 + w * 16 + n] = f2b(accx[reg]);
            bufy[p * 72 + w * 16 + n] = f2b(accy[reg]);
        }
    }
    __syncthreads();

    for (int g = tid; g < 896; g += 256) {    // coalesced 128B-segment writes
        int p = g >> 3, c = (g & 7) << 3;
        *(uint4*)(xp + (size_t)p * BN_ + row0 + c) = *(const uint4*)(bufx + p * 72 + c);
        *(uint4*)(yp + (size_t)p * BN_ + row0 + c) = *(const uint4*)(bufy + p * 72 + c);
    }
}

// ---------------------------------------------------------------------------
// Kernel 3: fused counting sort + rank + diff.  Packed histogram: y counts in
// low 16 (+1), x counts in high 16 (+0x10000); max count 16384 < 2^16 so the
// packed exclusive scan is field-independent (total 0x4000_4000, no carry).
// Proven R4 shape: 1024 thr x 16 elems, launch_bounds(1024,4) — ~100 VGPR,
// zero spill, wave-contiguous uint4 I/O.  UNCHANGED.
// ---------------------------------------------------------------------------
__device__ __forceinline__ int binof(float v) {
    int k = (int)((v + 8.0f) * 256.0f);
    return k < 0 ? 0 : (k > NBIN - 1 ? NBIN - 1 : k);
}

__device__ __forceinline__ void scan4(unsigned* hist, volatile unsigned* wsum, int t) {
    unsigned v[4], run = 0;
    #pragma unroll
    for (int i = 0; i < 4; ++i) { unsigned h = hist[t * 4 + i]; v[i] = run; run += h; }
    const int lane = t & 63, w = t >> 6;
    unsigned inc = run;
    #pragma unroll
    for (int off = 1; off < 64; off <<= 1) {
        unsigned nbr = __shfl_up(inc, off, 64);
        if (lane >= off) inc += nbr;
    }
    if (lane == 63) wsum[w] = inc;
    __syncthreads();
    if (t == 0) {
        unsigned r2 = 0;
        #pragma unroll
        for (int i = 0; i < 16; ++i) { unsigned h = wsum[i]; wsum[i] = r2; r2 += h; }
    }
    __syncthreads();
    unsigned base = wsum[w] + (inc - run);
    #pragma unroll
    for (int i = 0; i < 4; ++i) hist[t * 4 + i] = base + v[i];
}

__global__ __launch_bounds__(1024, 4) void k_sortdiff(
    const unsigned short* __restrict__ xp, const unsigned short* __restrict__ yp,
    unsigned short* __restrict__ diff) {
    __shared__ unsigned hist[NBIN];           // 16 KB (packed y|x)
    __shared__ unsigned short ysort[N_];      // 32 KB
    __shared__ unsigned wsum[16];
    const int t = threadIdx.x;
    const unsigned* ypd = (const unsigned*)(yp + (size_t)blockIdx.x * N_);
    const unsigned* xpd = (const unsigned*)(xp + (size_t)blockIdx.x * N_);
    unsigned*       dfd = (unsigned*)(diff + (size_t)blockIdx.x * N_);

    // 16 elems/thread; wave-contiguous uint4 loads (lane-adjacent 16 B)
    unsigned yw[8], xw[8];
    #pragma unroll
    for (int i = 0; i < 2; ++i) {
        uint4 a = *(const uint4*)(ypd + i * 4096 + t * 4);
        yw[4*i] = a.x; yw[4*i+1] = a.y; yw[4*i+2] = a.z; yw[4*i+3] = a.w;
        uint4 c = *(const uint4*)(xpd + i * 4096 + t * 4);
        xw[4*i] = c.x; xw[4*i+1] = c.y; xw[4*i+2] = c.z; xw[4*i+3] = c.w;
    }

    #pragma unroll
    for (int i = 0; i < 4; ++i) hist[t + i * 1024] = 0;
    __syncthreads();

    // ---- single packed count pass (returning: own field IS intra-bin idx) ----
    unsigned jy[8], jx[8];
    #pragma unroll
    for (int k = 0; k < 8; ++k) {
        unsigned j0 = atomicAdd(&hist[binof(b2f((unsigned short)(yw[k] & 0xffff)))], 1u);
        unsigned j1 = atomicAdd(&hist[binof(b2f((unsigned short)(yw[k] >> 16)))], 1u);
        jy[k] = (j0 & 0xffffu) | (j1 << 16);
        unsigned i0 = atomicAdd(&hist[binof(b2f((unsigned short)(xw[k] & 0xffff)))], 0x10000u);
        unsigned i1 = atomicAdd(&hist[binof(b2f((unsigned short)(xw[k] >> 16)))], 0x10000u);
        jx[k] = (i0 >> 16) | (i1 & 0xffff0000u);
    }
    __syncthreads();
    scan4(hist, wsum, t);                     // packed exclusive prefix, both fields
    __syncthreads();

    // scatter y into LDS (low field) and fold x rank into jx (high field)
    #pragma unroll
    for (int k = 0; k < 8; ++k) {
        unsigned short e0 = (unsigned short)(yw[k] & 0xffff);
        unsigned short e1 = (unsigned short)(yw[k] >> 16);
        ysort[(hist[binof(b2f(e0))] & 0xffffu) + (jy[k] & 0xffffu)] = e0;
        ysort[(hist[binof(b2f(e1))] & 0xffffu) + (jy[k] >> 16)]     = e1;
        unsigned r0 = (hist[binof(b2f((unsigned short)(xw[k] & 0xffff)))] >> 16) + (jx[k] & 0xffffu);
        unsigned r1 = (hist[binof(b2f((unsigned short)(xw[k] >> 16)))] >> 16) + (jx[k] >> 16);
        jx[k] = r0 | (r1 << 16);
    }
    __syncthreads();

    // gather transported y, write diff (wave-contiguous uint4 stores)
    #pragma unroll
    for (int i = 0; i < 2; ++i) {
        unsigned o[4];
        #pragma unroll
        for (int q = 0; q < 4; ++q) {
            int k = 4*i + q;
            float x0 = b2f((unsigned short)(xw[k] & 0xffff));
            float x1 = b2f((unsigned short)(xw[k] >> 16));
            unsigned short d0 = f2b(b2f(ysort[jx[k] & 0xffffu]) - x0);
            unsigned short d1 = f2b(b2f(ysort[jx[k] >> 16]) - x1);
            o[q] = (unsigned)d0 | ((unsigned)d1 << 16);
        }
        *(uint4*)(dfd + i * 4096 + t * 4) = make_uint4(o[0], o[1], o[2], o[3]);
    }
}

// ---------------------------------------------------------------------------
// Kernel 4: combine via bf16 MFMA, transpose fused into the LDS stage.
// R4 fix (Common-mistake #7): thbT (32 KB) is L2-resident — B-fragments load
// straight from global instead of a 34.8 KB LDS copy + 2048-elem staging
// loop.  LDS keeps only the genuine transpose tile Lp (17.4 KB) ->
// launch_bounds(256,4): 4 blocks/CU, 16 waves/CU (was 3/12).  ONE barrier.
// Lp: diff[p][row0..+64] pair-packed (dword = {k even lo16, k odd hi16});
// k2 rows 50..63 zeroed = NaN-safe K-pad.  A-frag ds_read_b32 at (k2)*68+r
// dwords — 2-way bank aliasing = free (m136).  C[m=row][n=d]; out = x + C/P.
// ---------------------------------------------------------------------------
__global__ __launch_bounds__(256, 4) void k_comb(
    const float* __restrict__ x, const unsigned short* __restrict__ diff,
    const unsigned short* __restrict__ thbT, float* __restrict__ out) {
    __shared__ unsigned Lp[64 * 68];          // 17,408 B  [k2][row] pair-packed
    const int tid  = threadIdx.x;
    const int w    = tid >> 6;                // wave -> rows w*16..+15
    const int lane = tid & 63;
    const int n16  = lane & 15;
    const int quad = lane >> 4;
    const int row0 = blockIdx.x * 64;

    for (int g = tid; g < 952; g += 256) Lp[50 * 68 + g] = 0;   // k2=50..63 pad
    for (int g = tid; g < 400; g += 256) {    // 50 p-pairs x 8 row-groups
        int p2 = g >> 3, rg = (g & 7) << 3;
        uint4 a = *(const uint4*)(diff + (size_t)(2 * p2) * BN_ + row0 + rg);
        uint4 b = *(const uint4*)(diff + (size_t)(2 * p2 + 1) * BN_ + row0 + rg);
        unsigned* dst = Lp + p2 * 68 + rg;
        dst[0] = (a.x & 0xffffu) | (b.x << 16);
        dst[1] = (a.x >> 16)     | (b.x & 0xffff0000u);
        dst[2] = (a.y & 0xffffu) | (b.y << 16);
        dst[3] = (a.y >> 16)     | (b.y & 0xffff0000u);
        dst[4] = (a.z & 0xffffu) | (b.z << 16);
        dst[5] = (a.z >> 16)     | (b.z & 0xffff0000u);
        dst[6] = (a.w & 0xffffu) | (b.w << 16);
        dst[7] = (a.w >> 16)     | (b.w & 0xffff0000u);
    }
    __syncthreads();

    // A-frags: lane row r = w*16+n16, k = ks*32 + quad*8 + 0..7
    const int r = w * 16 + n16;
    short8 af[4];
    #pragma unroll
    for (int ks = 0; ks < 4; ++ks) {
        union { unsigned u[4]; short8 v; } tu;
        #pragma unroll
        for (int m = 0; m < 4; ++m)
            tu.u[m] = Lp[(ks * 16 + quad * 4 + m) * 68 + r];
        af[ks] = tu.v;
    }

    floatx4 acc[8];
    #pragma unroll
    for (int nt = 0; nt < 8; ++nt) {
        acc[nt] = (floatx4){0.f, 0.f, 0.f, 0.f};
        #pragma unroll
        for (int ks = 0; ks < 4; ++ks) {
            short8 b = *(const short8*)(thbT + (nt * 16 + n16) * KPAD + ks * 32 + quad * 8);
            acc[nt] = __builtin_amdgcn_mfma_f32_16x16x32_bf16(af[ks], b, acc[nt], 0, 0, 0);
        }
    }

    const float invP = 1.0f / (float)P_;
    const size_t rbase = (size_t)(row0 + w * 16 + quad * 4) * D_ + n16;
    #pragma unroll
    for (int nt = 0; nt < 8; ++nt)
        #pragma unroll
        for (int reg = 0; reg < 4; ++reg) {
            size_t o = rbase + (size_t)reg * D_ + nt * 16;
            out[o] = fmaf(acc[nt][reg], invP, x[o]);
        }
}

// ---------------------------------------------------------------------------
// Workspace (bytes): thb[0, 32KB) thbT[32KB, 64KB) xp[64KB, +13.1MB)
// yp(+13.1MB) => ~26.3 MB. diff overwrites xp in place.
// ---------------------------------------------------------------------------
extern "C" void kernel_launch(void* const* d_in, const int* in_sizes, int n_in,
                              void* d_out, int out_size, void* d_ws, size_t ws_size,
                              hipStream_t stream) {
    const float* x  = (const float*)d_in[0];
    const float* y  = (const float*)d_in[1];
    const float* th = (const float*)d_in[2];
    float* out = (float*)d_out;
    char*  wsb = (char*)d_ws;

    unsigned short* thb  = (unsigned short*)wsb;
    unsigned short* thbT = (unsigned short*)(wsb + 32768);
    unsigned short* xpb  = (unsigned short*)(wsb + 65536);
    unsigned short* ypb  = xpb + PBN_;

    k_norm<<<128, 128, 0, stream>>>(th, thb, thbT);
    k_proj<<<BN_ / 64, 256, 0, stream>>>(x, y, thb, xpb, ypb);
    k_sortdiff<<<P_ * B_, 1024, 0, stream>>>(xpb, ypb, xpb);
    k_comb<<<BN_ / 64, 256, 0, stream>>>(x, xpb, thbT, out);
}

// Round 6
// 151.231 us; speedup vs baseline: 1.0750x; 1.0750x over previous
//
#include <hip/hip_runtime.h>
#include <hip/hip_bf16.h>

#define B_    4
#define N_    16384
#define D_    128
#define P_    100
#define BN_   65536      // B_*N_
#define PBN_  6553600    // P_*BN_
#define PPAD  112        // P padded to 7*16 MFMA p-tiles (k_proj)
#define KPAD  128        // P padded to 128 for k_comb's K dimension
#define NBIN  4096

typedef __attribute__((ext_vector_type(8))) short short8;   // 8 bf16 = 4 VGPR
typedef __attribute__((ext_vector_type(4))) float floatx4;  // MFMA C/D

// bf16 <-> f32 via raw bits (RNE; inputs are finite)
__device__ __forceinline__ unsigned short f2b(float f) {
    unsigned u = __float_as_uint(f);
    return (unsigned short)((u + 0x7FFFu + ((u >> 16) & 1u)) >> 16);
}
__device__ __forceinline__ float b2f(unsigned short h) {
    return __uint_as_float(((unsigned)h) << 16);
}

// ---------------------------------------------------------------------------
// Kernel 1: theta normalization -> thb[p][d] (k_proj A-operand, rows >=100
// zero) and thbT[d][p] (k_comb B-operand, cols >=100 zero; NaN-safe K-pad).
// ---------------------------------------------------------------------------
__global__ void k_norm(const float* __restrict__ th,
                       unsigned short* __restrict__ thb,
                       unsigned short* __restrict__ thbT) {
    int p = blockIdx.x;       // 0..127
    int d = threadIdx.x;      // 0..127
    float v = 0.f;
    if (p < P_) v = th[p * D_ + d];
    float s = v * v;
    #pragma unroll
    for (int o = 32; o > 0; o >>= 1) s += __shfl_down(s, o, 64);
    __shared__ float red[2];
    if ((d & 63) == 0) red[d >> 6] = s;
    __syncthreads();
    float norm = fmaxf(sqrtf(red[0] + red[1]), 1e-12f);
    unsigned short r = f2b(v / norm);       // p>=100 -> 0/1e-12 = +0
    if (p < PPAD) thb[p * D_ + d] = r;
    thbT[d * KPAD + p] = r;
}

// ---------------------------------------------------------------------------
// Kernel 2: projections via bf16 MFMA 16x16x32.
// R5 post-mortem: theta MUST stay in LDS (direct global A-frags = 64 scattered
// 16B segments per instr x 28/wave -> regression).  R6: keep LDS theta, drop
// the OUTPUT-coalescing bufs instead — store C-fragments straight to global
// (per instr: 4x32B segments of 4 consecutive p-rows; block covers each
// p-row's full 128B -> L2 write-combines full lines).  LDS 62.7 -> 30.5 KB:
// 4-5 blocks/CU (16-20 waves, was 8), one barrier, no LDS round trip for
// outputs.  Live state ~70 VGPR < cap 128 of launch_bounds(256,4) - no spill.
// ---------------------------------------------------------------------------
__global__ __launch_bounds__(256, 4) void k_proj(
    const float* __restrict__ x, const float* __restrict__ y,
    const unsigned short* __restrict__ thb,
    unsigned short* __restrict__ xp, unsigned short* __restrict__ yp) {
    __shared__ unsigned short th_s[15232];    // [112][136] 30,464 B
    const int tid  = threadIdx.x;
    const int w    = tid >> 6;                // wave 0..3 -> rows w*16..+15
    const int lane = tid & 63;
    const int n    = lane & 15;
    const int quad = lane >> 4;
    const int row0 = blockIdx.x * 64;

    for (int g = tid; g < 1792; g += 256) {   // theta 112x128 bf16 -> LDS
        int r = g >> 4, c = (g & 15) << 3;
        *(uint4*)(th_s + r * 136 + c) = *(const uint4*)(thb + r * D_ + c);
    }

    // direct global loads of this lane's B-fragments, convert in-register
    const float* xr = x + (size_t)(row0 + w * 16 + n) * D_ + quad * 8;
    const float* yr = y + (size_t)(row0 + w * 16 + n) * D_ + quad * 8;
    short8 bx[4], by[4];
    {
        float4 lx[8];
        #pragma unroll
        for (int ks = 0; ks < 4; ++ks) {
            lx[2*ks]   = *(const float4*)(xr + ks * 32);
            lx[2*ks+1] = *(const float4*)(xr + ks * 32 + 4);
        }
        #pragma unroll
        for (int ks = 0; ks < 4; ++ks) {
            short8 t;
            t[0] = (short)f2b(lx[2*ks].x);   t[1] = (short)f2b(lx[2*ks].y);
            t[2] = (short)f2b(lx[2*ks].z);   t[3] = (short)f2b(lx[2*ks].w);
            t[4] = (short)f2b(lx[2*ks+1].x); t[5] = (short)f2b(lx[2*ks+1].y);
            t[6] = (short)f2b(lx[2*ks+1].z); t[7] = (short)f2b(lx[2*ks+1].w);
            bx[ks] = t;
        }
    }
    {
        float4 ly[8];
        #pragma unroll
        for (int ks = 0; ks < 4; ++ks) {
            ly[2*ks]   = *(const float4*)(yr + ks * 32);
            ly[2*ks+1] = *(const float4*)(yr + ks * 32 + 4);
        }
        #pragma unroll
        for (int ks = 0; ks < 4; ++ks) {
            short8 t;
            t[0] = (short)f2b(ly[2*ks].x);   t[1] = (short)f2b(ly[2*ks].y);
            t[2] = (short)f2b(ly[2*ks].z);   t[3] = (short)f2b(ly[2*ks].w);
            t[4] = (short)f2b(ly[2*ks+1].x); t[5] = (short)f2b(ly[2*ks+1].y);
            t[6] = (short)f2b(ly[2*ks+1].z); t[7] = (short)f2b(ly[2*ks+1].w);
            by[ks] = t;
        }
    }
    __syncthreads();                          // theta staged

    const size_t obase = row0 + w * 16 + n;   // this lane's output column
    #pragma unroll
    for (int pt = 0; pt < 7; ++pt) {
        floatx4 accx = {0.f, 0.f, 0.f, 0.f};
        floatx4 accy = {0.f, 0.f, 0.f, 0.f};
        #pragma unroll
        for (int ks = 0; ks < 4; ++ks) {
            short8 a = *(const short8*)(th_s + (pt * 16 + n) * 136 + ks * 32 + quad * 8);
            accx = __builtin_amdgcn_mfma_f32_16x16x32_bf16(a, bx[ks], accx, 0, 0, 0);
            accy = __builtin_amdgcn_mfma_f32_16x16x32_bf16(a, by[ks], accy, 0, 0, 0);
        }
        #pragma unroll
        for (int reg = 0; reg < 4; ++reg) {   // direct fire-and-forget stores
            size_t o = (size_t)(pt * 16 + quad * 4 + reg) * BN_ + obase;
            xp[o] = f2b(accx[reg]);
            yp[o] = f2b(accy[reg]);
        }
    }
}

// ---------------------------------------------------------------------------
// Kernel 3: fused counting sort + rank + diff.  Packed histogram: y counts in
// low 16 (+1), x counts in high 16 (+0x10000); max count 16384 < 2^16 so the
// packed exclusive scan is field-independent (total 0x4000_4000, no carry).
// Proven R4 shape: 1024 thr x 16 elems, launch_bounds(1024,4) — ~100 VGPR,
// zero spill, wave-contiguous uint4 I/O.  UNCHANGED.
// ---------------------------------------------------------------------------
__device__ __forceinline__ int binof(float v) {
    int k = (int)((v + 8.0f) * 256.0f);
    return k < 0 ? 0 : (k > NBIN - 1 ? NBIN - 1 : k);
}

__device__ __forceinline__ void scan4(unsigned* hist, volatile unsigned* wsum, int t) {
    unsigned v[4], run = 0;
    #pragma unroll
    for (int i = 0; i < 4; ++i) { unsigned h = hist[t * 4 + i]; v[i] = run; run += h; }
    const int lane = t & 63, w = t >> 6;
    unsigned inc = run;
    #pragma unroll
    for (int off = 1; off < 64; off <<= 1) {
        unsigned nbr = __shfl_up(inc, off, 64);
        if (lane >= off) inc += nbr;
    }
    if (lane == 63) wsum[w] = inc;
    __syncthreads();
    if (t == 0) {
        unsigned r2 = 0;
        #pragma unroll
        for (int i = 0; i < 16; ++i) { unsigned h = wsum[i]; wsum[i] = r2; r2 += h; }
    }
    __syncthreads();
    unsigned base = wsum[w] + (inc - run);
    #pragma unroll
    for (int i = 0; i < 4; ++i) hist[t * 4 + i] = base + v[i];
}

__global__ __launch_bounds__(1024, 4) void k_sortdiff(
    const unsigned short* __restrict__ xp, const unsigned short* __restrict__ yp,
    unsigned short* __restrict__ diff) {
    __shared__ unsigned hist[NBIN];           // 16 KB (packed y|x)
    __shared__ unsigned short ysort[N_];      // 32 KB
    __shared__ unsigned wsum[16];
    const int t = threadIdx.x;
    const unsigned* ypd = (const unsigned*)(yp + (size_t)blockIdx.x * N_);
    const unsigned* xpd = (const unsigned*)(xp + (size_t)blockIdx.x * N_);
    unsigned*       dfd = (unsigned*)(diff + (size_t)blockIdx.x * N_);

    // 16 elems/thread; wave-contiguous uint4 loads (lane-adjacent 16 B)
    unsigned yw[8], xw[8];
    #pragma unroll
    for (int i = 0; i < 2; ++i) {
        uint4 a = *(const uint4*)(ypd + i * 4096 + t * 4);
        yw[4*i] = a.x; yw[4*i+1] = a.y; yw[4*i+2] = a.z; yw[4*i+3] = a.w;
        uint4 c = *(const uint4*)(xpd + i * 4096 + t * 4);
        xw[4*i] = c.x; xw[4*i+1] = c.y; xw[4*i+2] = c.z; xw[4*i+3] = c.w;
    }

    #pragma unroll
    for (int i = 0; i < 4; ++i) hist[t + i * 1024] = 0;
    __syncthreads();

    // ---- single packed count pass (returning: own field IS intra-bin idx) ----
    unsigned jy[8], jx[8];
    #pragma unroll
    for (int k = 0; k < 8; ++k) {
        unsigned j0 = atomicAdd(&hist[binof(b2f((unsigned short)(yw[k] & 0xffff)))], 1u);
        unsigned j1 = atomicAdd(&hist[binof(b2f((unsigned short)(yw[k] >> 16)))], 1u);
        jy[k] = (j0 & 0xffffu) | (j1 << 16);
        unsigned i0 = atomicAdd(&hist[binof(b2f((unsigned short)(xw[k] & 0xffff)))], 0x10000u);
        unsigned i1 = atomicAdd(&hist[binof(b2f((unsigned short)(xw[k] >> 16)))], 0x10000u);
        jx[k] = (i0 >> 16) | (i1 & 0xffff0000u);
    }
    __syncthreads();
    scan4(hist, wsum, t);                     // packed exclusive prefix, both fields
    __syncthreads();

    // scatter y into LDS (low field) and fold x rank into jx (high field)
    #pragma unroll
    for (int k = 0; k < 8; ++k) {
        unsigned short e0 = (unsigned short)(yw[k] & 0xffff);
        unsigned short e1 = (unsigned short)(yw[k] >> 16);
        ysort[(hist[binof(b2f(e0))] & 0xffffu) + (jy[k] & 0xffffu)] = e0;
        ysort[(hist[binof(b2f(e1))] & 0xffffu) + (jy[k] >> 16)]     = e1;
        unsigned r0 = (hist[binof(b2f((unsigned short)(xw[k] & 0xffff)))] >> 16) + (jx[k] & 0xffffu);
        unsigned r1 = (hist[binof(b2f((unsigned short)(xw[k] >> 16)))] >> 16) + (jx[k] >> 16);
        jx[k] = r0 | (r1 << 16);
    }
    __syncthreads();

    // gather transported y, write diff (wave-contiguous uint4 stores)
    #pragma unroll
    for (int i = 0; i < 2; ++i) {
        unsigned o[4];
        #pragma unroll
        for (int q = 0; q < 4; ++q) {
            int k = 4*i + q;
            float x0 = b2f((unsigned short)(xw[k] & 0xffff));
            float x1 = b2f((unsigned short)(xw[k] >> 16));
            unsigned short d0 = f2b(b2f(ysort[jx[k] & 0xffffu]) - x0);
            unsigned short d1 = f2b(b2f(ysort[jx[k] >> 16]) - x1);
            o[q] = (unsigned)d0 | ((unsigned)d1 << 16);
        }
        *(uint4*)(dfd + i * 4096 + t * 4) = make_uint4(o[0], o[1], o[2], o[3]);
    }
}

// ---------------------------------------------------------------------------
// Kernel 4: combine via bf16 MFMA, transpose fused into the LDS stage.
// R4-proven version (thbT staged in LDS — R5 showed direct global B-frags
// regress due to scattered gathers).  Lp: diff[p][row0..+64] pair-packed
// (dword = {k even lo16, k odd hi16}); k2 rows 50..63 zeroed = NaN-safe
// K-pad.  A-frag ds_read_b32 at (k2)*68+r dwords — 2-way bank aliasing =
// free (m136).  C[m=row][n=d]; out = x + C/P.  LDS 52.2 KB -> 3 blocks/CU.
// ---------------------------------------------------------------------------
__global__ __launch_bounds__(256) void k_comb(
    const float* __restrict__ x, const unsigned short* __restrict__ diff,
    const unsigned short* __restrict__ thbT, float* __restrict__ out) {
    __shared__ unsigned short ths[128 * 136]; // 34,816 B
    __shared__ unsigned Lp[64 * 68];          // 17,408 B  [k2][row] pair-packed
    const int tid  = threadIdx.x;
    const int w    = tid >> 6;                // wave -> rows w*16..+15
    const int lane = tid & 63;
    const int n16  = lane & 15;
    const int quad = lane >> 4;
    const int row0 = blockIdx.x * 64;

    for (int g = tid; g < 2048; g += 256) {   // thbT 128x128 bf16 -> LDS
        int r = g >> 4, c = (g & 15) << 3;
        *(uint4*)(ths + r * 136 + c) = *(const uint4*)(thbT + r * KPAD + c);
    }
    for (int g = tid; g < 952; g += 256) Lp[50 * 68 + g] = 0;   // k2=50..63 pad
    for (int g = tid; g < 400; g += 256) {    // 50 p-pairs x 8 row-groups
        int p2 = g >> 3, rg = (g & 7) << 3;
        uint4 a = *(const uint4*)(diff + (size_t)(2 * p2) * BN_ + row0 + rg);
        uint4 b = *(const uint4*)(diff + (size_t)(2 * p2 + 1) * BN_ + row0 + rg);
        unsigned* dst = Lp + p2 * 68 + rg;
        dst[0] = (a.x & 0xffffu) | (b.x << 16);
        dst[1] = (a.x >> 16)     | (b.x & 0xffff0000u);
        dst[2] = (a.y & 0xffffu) | (b.y << 16);
        dst[3] = (a.y >> 16)     | (b.y & 0xffff0000u);
        dst[4] = (a.z & 0xffffu) | (b.z << 16);
        dst[5] = (a.z >> 16)     | (b.z & 0xffff0000u);
        dst[6] = (a.w & 0xffffu) | (b.w << 16);
        dst[7] = (a.w >> 16)     | (b.w & 0xffff0000u);
    }
    __syncthreads();

    // A-frags: lane row r = w*16+n16, k = ks*32 + quad*8 + 0..7
    const int r = w * 16 + n16;
    short8 af[4];
    #pragma unroll
    for (int ks = 0; ks < 4; ++ks) {
        union { unsigned u[4]; short8 v; } tu;
        #pragma unroll
        for (int m = 0; m < 4; ++m)
            tu.u[m] = Lp[(ks * 16 + quad * 4 + m) * 68 + r];
        af[ks] = tu.v;
    }

    floatx4 acc[8];
    #pragma unroll
    for (int nt = 0; nt < 8; ++nt) {
        acc[nt] = (floatx4){0.f, 0.f, 0.f, 0.f};
        #pragma unroll
        for (int ks = 0; ks < 4; ++ks) {
            short8 b = *(const short8*)(ths + (nt * 16 + n16) * 136 + ks * 32 + quad * 8);
            acc[nt] = __builtin_amdgcn_mfma_f32_16x16x32_bf16(af[ks], b, acc[nt], 0, 0, 0);
        }
    }

    const float invP = 1.0f / (float)P_;
    const size_t rbase = (size_t)(row0 + w * 16 + quad * 4) * D_ + n16;
    #pragma unroll
    for (int nt = 0; nt < 8; ++nt)
        #pragma unroll
        for (int reg = 0; reg < 4; ++reg) {
            size_t o = rbase + (size_t)reg * D_ + nt * 16;
            out[o] = fmaf(acc[nt][reg], invP, x[o]);
        }
}

// ---------------------------------------------------------------------------
// Workspace (bytes): thb[0, 32KB) thbT[32KB, 64KB) xp[64KB, +13.1MB)
// yp(+13.1MB) => ~26.3 MB. diff overwrites xp in place.
// ---------------------------------------------------------------------------
extern "C" void kernel_launch(void* const* d_in, const int* in_sizes, int n_in,
                              void* d_out, int out_size, void* d_ws, size_t ws_size,
                              hipStream_t stream) {
    const float* x  = (const float*)d_in[0];
    const float* y  = (const float*)d_in[1];
    const float* th = (const float*)d_in[2];
    float* out = (float*)d_out;
    char*  wsb = (char*)d_ws;

    unsigned short* thb  = (unsigned short*)wsb;
    unsigned short* thbT = (unsigned short*)(wsb + 32768);
    unsigned short* xpb  = (unsigned short*)(wsb + 65536);
    unsigned short* ypb  = xpb + PBN_;

    k_norm<<<128, 128, 0, stream>>>(th, thb, thbT);
    k_proj<<<BN_ / 64, 256, 0, stream>>>(x, y, thb, xpb, ypb);
    k_sortdiff<<<P_ * B_, 1024, 0, stream>>>(xpb, ypb, xpb);
    k_comb<<<BN_ / 64, 256, 0, stream>>>(x, xpb, thbT, out);
}

// Round 7
// 144.227 us; speedup vs baseline: 1.1272x; 1.0486x over previous
//
#include <hip/hip_runtime.h>
#include <hip/hip_bf16.h>

#define B_    4
#define N_    16384
#define D_    128
#define P_    100
#define BN_   65536      // B_*N_
#define PBN_  6553600    // P_*BN_
#define PPAD  112        // P padded to 7*16 MFMA p-tiles (k_proj)
#define KPAD  128        // P padded to 128 for k_comb's K dimension
#define NBIN  4096

typedef __attribute__((ext_vector_type(8))) short short8;   // 8 bf16 = 4 VGPR
typedef __attribute__((ext_vector_type(4))) float floatx4;  // MFMA C/D

// bf16 <-> f32 via raw bits (RNE; inputs are finite)
__device__ __forceinline__ unsigned short f2b(float f) {
    unsigned u = __float_as_uint(f);
    return (unsigned short)((u + 0x7FFFu + ((u >> 16) & 1u)) >> 16);
}
__device__ __forceinline__ float b2f(unsigned short h) {
    return __uint_as_float(((unsigned)h) << 16);
}

// ---------------------------------------------------------------------------
// Kernel 1: theta normalization -> thb[p][d] (k_proj A-operand, rows >=100
// zero) and thbT[d][p] (k_comb B-operand, cols >=100 zero; NaN-safe K-pad).
// ---------------------------------------------------------------------------
__global__ void k_norm(const float* __restrict__ th,
                       unsigned short* __restrict__ thb,
                       unsigned short* __restrict__ thbT) {
    int p = blockIdx.x;       // 0..127
    int d = threadIdx.x;      // 0..127
    float v = 0.f;
    if (p < P_) v = th[p * D_ + d];
    float s = v * v;
    #pragma unroll
    for (int o = 32; o > 0; o >>= 1) s += __shfl_down(s, o, 64);
    __shared__ float red[2];
    if ((d & 63) == 0) red[d >> 6] = s;
    __syncthreads();
    float norm = fmaxf(sqrtf(red[0] + red[1]), 1e-12f);
    unsigned short r = f2b(v / norm);       // p>=100 -> 0/1e-12 = +0
    if (p < PPAD) thb[p * D_ + d] = r;
    thbT[d * KPAD + p] = r;
}

// ---------------------------------------------------------------------------
// Kernel 2: projections via bf16 MFMA 16x16x32.
// R7: single SHARED output buffer (x then y) -> LDS 62.7 -> 46.6 KB ->
// 3 blocks/CU, 12 waves/CU (was 2/8).  MFMA loop computes accx+accy together
// (A-frags read once); accx -> buf -> coalesced xp write; accy HELD in 28
// VGPRs (ay[7], static indices) then dumped to the same buf -> yp write.
// Also fixes the latent overflow: store loop now g<800 (p<100 only) — the
// old g<896 wrote xp rows 100..111 onto ypb rows 0..11 (same-block race).
// Peak live state ~100 VGPR < cap 128 of launch_bounds(256,4) — no spill.
// ---------------------------------------------------------------------------
__global__ __launch_bounds__(256, 4) void k_proj(
    const float* __restrict__ x, const float* __restrict__ y,
    const unsigned short* __restrict__ thb,
    unsigned short* __restrict__ xp, unsigned short* __restrict__ yp) {
    __shared__ unsigned short th_s[15232];    // [112][136] 30,464 B
    __shared__ unsigned short buf[8064];      // [112][72]  16,128 B (x, then y)
    const int tid  = threadIdx.x;
    const int w    = tid >> 6;                // wave 0..3 -> rows w*16..+15
    const int lane = tid & 63;
    const int n    = lane & 15;
    const int quad = lane >> 4;
    const int row0 = blockIdx.x * 64;

    for (int g = tid; g < 1792; g += 256) {   // theta 112x128 bf16 -> LDS
        int r = g >> 4, c = (g & 15) << 3;
        *(uint4*)(th_s + r * 136 + c) = *(const uint4*)(thb + r * D_ + c);
    }

    // direct global loads of this lane's B-fragments, convert in-register
    const float* xr = x + (size_t)(row0 + w * 16 + n) * D_ + quad * 8;
    const float* yr = y + (size_t)(row0 + w * 16 + n) * D_ + quad * 8;
    short8 bx[4], by[4];
    {
        float4 lx[8];
        #pragma unroll
        for (int ks = 0; ks < 4; ++ks) {
            lx[2*ks]   = *(const float4*)(xr + ks * 32);
            lx[2*ks+1] = *(const float4*)(xr + ks * 32 + 4);
        }
        #pragma unroll
        for (int ks = 0; ks < 4; ++ks) {
            short8 t;
            t[0] = (short)f2b(lx[2*ks].x);   t[1] = (short)f2b(lx[2*ks].y);
            t[2] = (short)f2b(lx[2*ks].z);   t[3] = (short)f2b(lx[2*ks].w);
            t[4] = (short)f2b(lx[2*ks+1].x); t[5] = (short)f2b(lx[2*ks+1].y);
            t[6] = (short)f2b(lx[2*ks+1].z); t[7] = (short)f2b(lx[2*ks+1].w);
            bx[ks] = t;
        }
    }
    {
        float4 ly[8];
        #pragma unroll
        for (int ks = 0; ks < 4; ++ks) {
            ly[2*ks]   = *(const float4*)(yr + ks * 32);
            ly[2*ks+1] = *(const float4*)(yr + ks * 32 + 4);
        }
        #pragma unroll
        for (int ks = 0; ks < 4; ++ks) {
            short8 t;
            t[0] = (short)f2b(ly[2*ks].x);   t[1] = (short)f2b(ly[2*ks].y);
            t[2] = (short)f2b(ly[2*ks].z);   t[3] = (short)f2b(ly[2*ks].w);
            t[4] = (short)f2b(ly[2*ks+1].x); t[5] = (short)f2b(ly[2*ks+1].y);
            t[6] = (short)f2b(ly[2*ks+1].z); t[7] = (short)f2b(ly[2*ks+1].w);
            by[ks] = t;
        }
    }
    __syncthreads();                          // theta staged

    floatx4 ay[7];                            // held y accumulators (28 VGPR)
    #pragma unroll
    for (int pt = 0; pt < 7; ++pt) {
        floatx4 accx = {0.f, 0.f, 0.f, 0.f};
        floatx4 accy = {0.f, 0.f, 0.f, 0.f};
        #pragma unroll
        for (int ks = 0; ks < 4; ++ks) {
            short8 a = *(const short8*)(th_s + (pt * 16 + n) * 136 + ks * 32 + quad * 8);
            accx = __builtin_amdgcn_mfma_f32_16x16x32_bf16(a, bx[ks], accx, 0, 0, 0);
            accy = __builtin_amdgcn_mfma_f32_16x16x32_bf16(a, by[ks], accy, 0, 0, 0);
        }
        #pragma unroll
        for (int reg = 0; reg < 4; ++reg)
            buf[(pt * 16 + quad * 4 + reg) * 72 + w * 16 + n] = f2b(accx[reg]);
        ay[pt] = accy;
    }
    __syncthreads();                          // x results staged

    for (int g = tid; g < 800; g += 256) {    // coalesced xp writes, p<100 ONLY
        int p = g >> 3, c = (g & 7) << 3;
        *(uint4*)(xp + (size_t)p * BN_ + row0 + c) = *(const uint4*)(buf + p * 72 + c);
    }
    __syncthreads();                          // buf reads done -> reuse for y

    #pragma unroll
    for (int pt = 0; pt < 7; ++pt)
        #pragma unroll
        for (int reg = 0; reg < 4; ++reg)
            buf[(pt * 16 + quad * 4 + reg) * 72 + w * 16 + n] = f2b(ay[pt][reg]);
    __syncthreads();                          // y results staged

    for (int g = tid; g < 800; g += 256) {    // coalesced yp writes, p<100 ONLY
        int p = g >> 3, c = (g & 7) << 3;
        *(uint4*)(yp + (size_t)p * BN_ + row0 + c) = *(const uint4*)(buf + p * 72 + c);
    }
}

// ---------------------------------------------------------------------------
// Kernel 3: fused counting sort + rank + diff.  Packed histogram: y counts in
// low 16 (+1), x counts in high 16 (+0x10000); max count 16384 < 2^16 so the
// packed exclusive scan is field-independent (total 0x4000_4000, no carry).
// Proven R4 shape: 1024 thr x 16 elems, launch_bounds(1024,4) — ~100 VGPR,
// zero spill, wave-contiguous uint4 I/O.  UNCHANGED.
// ---------------------------------------------------------------------------
__device__ __forceinline__ int binof(float v) {
    int k = (int)((v + 8.0f) * 256.0f);
    return k < 0 ? 0 : (k > NBIN - 1 ? NBIN - 1 : k);
}

__device__ __forceinline__ void scan4(unsigned* hist, volatile unsigned* wsum, int t) {
    unsigned v[4], run = 0;
    #pragma unroll
    for (int i = 0; i < 4; ++i) { unsigned h = hist[t * 4 + i]; v[i] = run; run += h; }
    const int lane = t & 63, w = t >> 6;
    unsigned inc = run;
    #pragma unroll
    for (int off = 1; off < 64; off <<= 1) {
        unsigned nbr = __shfl_up(inc, off, 64);
        if (lane >= off) inc += nbr;
    }
    if (lane == 63) wsum[w] = inc;
    __syncthreads();
    if (t == 0) {
        unsigned r2 = 0;
        #pragma unroll
        for (int i = 0; i < 16; ++i) { unsigned h = wsum[i]; wsum[i] = r2; r2 += h; }
    }
    __syncthreads();
    unsigned base = wsum[w] + (inc - run);
    #pragma unroll
    for (int i = 0; i < 4; ++i) hist[t * 4 + i] = base + v[i];
}

__global__ __launch_bounds__(1024, 4) void k_sortdiff(
    const unsigned short* __restrict__ xp, const unsigned short* __restrict__ yp,
    unsigned short* __restrict__ diff) {
    __shared__ unsigned hist[NBIN];           // 16 KB (packed y|x)
    __shared__ unsigned short ysort[N_];      // 32 KB
    __shared__ unsigned wsum[16];
    const int t = threadIdx.x;
    const unsigned* ypd = (const unsigned*)(yp + (size_t)blockIdx.x * N_);
    const unsigned* xpd = (const unsigned*)(xp + (size_t)blockIdx.x * N_);
    unsigned*       dfd = (unsigned*)(diff + (size_t)blockIdx.x * N_);

    // 16 elems/thread; wave-contiguous uint4 loads (lane-adjacent 16 B)
    unsigned yw[8], xw[8];
    #pragma unroll
    for (int i = 0; i < 2; ++i) {
        uint4 a = *(const uint4*)(ypd + i * 4096 + t * 4);
        yw[4*i] = a.x; yw[4*i+1] = a.y; yw[4*i+2] = a.z; yw[4*i+3] = a.w;
        uint4 c = *(const uint4*)(xpd + i * 4096 + t * 4);
        xw[4*i] = c.x; xw[4*i+1] = c.y; xw[4*i+2] = c.z; xw[4*i+3] = c.w;
    }

    #pragma unroll
    for (int i = 0; i < 4; ++i) hist[t + i * 1024] = 0;
    __syncthreads();

    // ---- single packed count pass (returning: own field IS intra-bin idx) ----
    unsigned jy[8], jx[8];
    #pragma unroll
    for (int k = 0; k < 8; ++k) {
        unsigned j0 = atomicAdd(&hist[binof(b2f((unsigned short)(yw[k] & 0xffff)))], 1u);
        unsigned j1 = atomicAdd(&hist[binof(b2f((unsigned short)(yw[k] >> 16)))], 1u);
        jy[k] = (j0 & 0xffffu) | (j1 << 16);
        unsigned i0 = atomicAdd(&hist[binof(b2f((unsigned short)(xw[k] & 0xffff)))], 0x10000u);
        unsigned i1 = atomicAdd(&hist[binof(b2f((unsigned short)(xw[k] >> 16)))], 0x10000u);
        jx[k] = (i0 >> 16) | (i1 & 0xffff0000u);
    }
    __syncthreads();
    scan4(hist, wsum, t);                     // packed exclusive prefix, both fields
    __syncthreads();

    // scatter y into LDS (low field) and fold x rank into jx (high field)
    #pragma unroll
    for (int k = 0; k < 8; ++k) {
        unsigned short e0 = (unsigned short)(yw[k] & 0xffff);
        unsigned short e1 = (unsigned short)(yw[k] >> 16);
        ysort[(hist[binof(b2f(e0))] & 0xffffu) + (jy[k] & 0xffffu)] = e0;
        ysort[(hist[binof(b2f(e1))] & 0xffffu) + (jy[k] >> 16)]     = e1;
        unsigned r0 = (hist[binof(b2f((unsigned short)(xw[k] & 0xffff)))] >> 16) + (jx[k] & 0xffffu);
        unsigned r1 = (hist[binof(b2f((unsigned short)(xw[k] >> 16)))] >> 16) + (jx[k] >> 16);
        jx[k] = r0 | (r1 << 16);
    }
    __syncthreads();

    // gather transported y, write diff (wave-contiguous uint4 stores)
    #pragma unroll
    for (int i = 0; i < 2; ++i) {
        unsigned o[4];
        #pragma unroll
        for (int q = 0; q < 4; ++q) {
            int k = 4*i + q;
            float x0 = b2f((unsigned short)(xw[k] & 0xffff));
            float x1 = b2f((unsigned short)(xw[k] >> 16));
            unsigned short d0 = f2b(b2f(ysort[jx[k] & 0xffffu]) - x0);
            unsigned short d1 = f2b(b2f(ysort[jx[k] >> 16]) - x1);
            o[q] = (unsigned)d0 | ((unsigned)d1 << 16);
        }
        *(uint4*)(dfd + i * 4096 + t * 4) = make_uint4(o[0], o[1], o[2], o[3]);
    }
}

// ---------------------------------------------------------------------------
// Kernel 4: combine via bf16 MFMA, transpose fused into the LDS stage.
// R4-proven version (thbT staged in LDS — R5 showed direct global B-frags
// regress due to scattered gathers).  Lp: diff[p][row0..+64] pair-packed
// (dword = {k even lo16, k odd hi16}); k2 rows 50..63 zeroed = NaN-safe
// K-pad.  A-frag ds_read_b32 at (k2)*68+r dwords — 2-way bank aliasing =
// free (m136).  C[m=row][n=d]; out = x + C/P.  LDS 52.2 KB -> 3 blocks/CU.
// ---------------------------------------------------------------------------
__global__ __launch_bounds__(256) void k_comb(
    const float* __restrict__ x, const unsigned short* __restrict__ diff,
    const unsigned short* __restrict__ thbT, float* __restrict__ out) {
    __shared__ unsigned short ths[128 * 136]; // 34,816 B
    __shared__ unsigned Lp[64 * 68];          // 17,408 B  [k2][row] pair-packed
    const int tid  = threadIdx.x;
    const int w    = tid >> 6;                // wave -> rows w*16..+15
    const int lane = tid & 63;
    const int n16  = lane & 15;
    const int quad = lane >> 4;
    const int row0 = blockIdx.x * 64;

    for (int g = tid; g < 2048; g += 256) {   // thbT 128x128 bf16 -> LDS
        int r = g >> 4, c = (g & 15) << 3;
        *(uint4*)(ths + r * 136 + c) = *(const uint4*)(thbT + r * KPAD + c);
    }
    for (int g = tid; g < 952; g += 256) Lp[50 * 68 + g] = 0;   // k2=50..63 pad
    for (int g = tid; g < 400; g += 256) {    // 50 p-pairs x 8 row-groups
        int p2 = g >> 3, rg = (g & 7) << 3;
        uint4 a = *(const uint4*)(diff + (size_t)(2 * p2) * BN_ + row0 + rg);
        uint4 b = *(const uint4*)(diff + (size_t)(2 * p2 + 1) * BN_ + row0 + rg);
        unsigned* dst = Lp + p2 * 68 + rg;
        dst[0] = (a.x & 0xffffu) | (b.x << 16);
        dst[1] = (a.x >> 16)     | (b.x & 0xffff0000u);
        dst[2] = (a.y & 0xffffu) | (b.y << 16);
        dst[3] = (a.y >> 16)     | (b.y & 0xffff0000u);
        dst[4] = (a.z & 0xffffu) | (b.z << 16);
        dst[5] = (a.z >> 16)     | (b.z & 0xffff0000u);
        dst[6] = (a.w & 0xffffu) | (b.w << 16);
        dst[7] = (a.w >> 16)     | (b.w & 0xffff0000u);
    }
    __syncthreads();

    // A-frags: lane row r = w*16+n16, k = ks*32 + quad*8 + 0..7
    const int r = w * 16 + n16;
    short8 af[4];
    #pragma unroll
    for (int ks = 0; ks < 4; ++ks) {
        union { unsigned u[4]; short8 v; } tu;
        #pragma unroll
        for (int m = 0; m < 4; ++m)
            tu.u[m] = Lp[(ks * 16 + quad * 4 + m) * 68 + r];
        af[ks] = tu.v;
    }

    floatx4 acc[8];
    #pragma unroll
    for (int nt = 0; nt < 8; ++nt) {
        acc[nt] = (floatx4){0.f, 0.f, 0.f, 0.f};
        #pragma unroll
        for (int ks = 0; ks < 4; ++ks) {
            short8 b = *(const short8*)(ths + (nt * 16 + n16) * 136 + ks * 32 + quad * 8);
            acc[nt] = __builtin_amdgcn_mfma_f32_16x16x32_bf16(af[ks], b, acc[nt], 0, 0, 0);
        }
    }

    const float invP = 1.0f / (float)P_;
    const size_t rbase = (size_t)(row0 + w * 16 + quad * 4) * D_ + n16;
    #pragma unroll
    for (int nt = 0; nt < 8; ++nt)
        #pragma unroll
        for (int reg = 0; reg < 4; ++reg) {
            size_t o = rbase + (size_t)reg * D_ + nt * 16;
            out[o] = fmaf(acc[nt][reg], invP, x[o]);
        }
}

// ---------------------------------------------------------------------------
// Workspace (bytes): thb[0, 32KB) thbT[32KB, 64KB) xp[64KB, +13.1MB)
// yp(+13.1MB) => ~26.3 MB. diff overwrites xp in place.
// ---------------------------------------------------------------------------
extern "C" void kernel_launch(void* const* d_in, const int* in_sizes, int n_in,
                              void* d_out, int out_size, void* d_ws, size_t ws_size,
                              hipStream_t stream) {
    const float* x  = (const float*)d_in[0];
    const float* y  = (const float*)d_in[1];
    const float* th = (const float*)d_in[2];
    float* out = (float*)d_out;
    char*  wsb = (char*)d_ws;

    unsigned short* thb  = (unsigned short*)wsb;
    unsigned short* thbT = (unsigned short*)(wsb + 32768);
    unsigned short* xpb  = (unsigned short*)(wsb + 65536);
    unsigned short* ypb  = xpb + PBN_;

    k_norm<<<128, 128, 0, stream>>>(th, thb, thbT);
    k_proj<<<BN_ / 64, 256, 0, stream>>>(x, y, thb, xpb, ypb);
    k_sortdiff<<<P_ * B_, 1024, 0, stream>>>(xpb, ypb, xpb);
    k_comb<<<BN_ / 64, 256, 0, stream>>>(x, xpb, thbT, out);
}

// Round 8
// 140.691 us; speedup vs baseline: 1.1555x; 1.0251x over previous
//
#include <hip/hip_runtime.h>
#include <hip/hip_bf16.h>

#define B_    4
#define N_    16384
#define D_    128
#define P_    100
#define BN_   65536      // B_*N_
#define PBN_  6553600    // P_*BN_
#define PPAD  112        // P padded to 7*16 MFMA p-tiles (k_proj)
#define KPAD  128        // P padded to 128 for k_comb's K dimension
#define NBIN  4096

typedef __attribute__((ext_vector_type(8))) short short8;   // 8 bf16 = 4 VGPR
typedef __attribute__((ext_vector_type(4))) float floatx4;  // MFMA C/D

// bf16 <-> f32 via raw bits (RNE; inputs are finite)
__device__ __forceinline__ unsigned short f2b(float f) {
    unsigned u = __float_as_uint(f);
    return (unsigned short)((u + 0x7FFFu + ((u >> 16) & 1u)) >> 16);
}
__device__ __forceinline__ float b2f(unsigned short h) {
    return __uint_as_float(((unsigned)h) << 16);
}

// ---------------------------------------------------------------------------
// Kernel 1: theta normalization -> thb[p][d] (k_proj A-operand, rows >=100
// zero) and thbT[d][p] (k_comb B-operand, cols >=100 zero; NaN-safe K-pad).
// ---------------------------------------------------------------------------
__global__ void k_norm(const float* __restrict__ th,
                       unsigned short* __restrict__ thb,
                       unsigned short* __restrict__ thbT) {
    int p = blockIdx.x;       // 0..127
    int d = threadIdx.x;      // 0..127
    float v = 0.f;
    if (p < P_) v = th[p * D_ + d];
    float s = v * v;
    #pragma unroll
    for (int o = 32; o > 0; o >>= 1) s += __shfl_down(s, o, 64);
    __shared__ float red[2];
    if ((d & 63) == 0) red[d >> 6] = s;
    __syncthreads();
    float norm = fmaxf(sqrtf(red[0] + red[1]), 1e-12f);
    unsigned short r = f2b(v / norm);       // p>=100 -> 0/1e-12 = +0
    if (p < PPAD) thb[p * D_ + d] = r;
    thbT[d * KPAD + p] = r;
}

// ---------------------------------------------------------------------------
// Kernel 2: projections via bf16 MFMA 16x16x32.
// R8: EXACT-OCCUPANCY variant.  R7's 46.6 KB LDS -> 3 blocks/CU -> grid 1024
// runs 1.33 scheduling rounds (last third at 1/3 utilization).  Shrink the
// shared output buffer to [64][72] (9.2 KB; 4 store phases: x p0-63, x
// p64-99, y p0-63, y p64-99 — all y accs held in ay[7] = 28 VGPR, R7-proven)
// -> LDS 39.7 KB -> 4 blocks/CU -> 1024 slots = grid -> 1.0 rounds,
// 16 waves/CU (was 12).  launch_bounds(256,4): cap 128 VGPR, live ~100.
// ---------------------------------------------------------------------------
__global__ __launch_bounds__(256, 4) void k_proj(
    const float* __restrict__ x, const float* __restrict__ y,
    const unsigned short* __restrict__ thb,
    unsigned short* __restrict__ xp, unsigned short* __restrict__ yp) {
    __shared__ unsigned short th_s[15232];    // [112][136] 30,464 B
    __shared__ unsigned short buf[4608];      // [64][72]    9,216 B
    const int tid  = threadIdx.x;
    const int w    = tid >> 6;                // wave 0..3 -> rows w*16..+15
    const int lane = tid & 63;
    const int n    = lane & 15;
    const int quad = lane >> 4;
    const int row0 = blockIdx.x * 64;

    for (int g = tid; g < 1792; g += 256) {   // theta 112x128 bf16 -> LDS
        int r = g >> 4, c = (g & 15) << 3;
        *(uint4*)(th_s + r * 136 + c) = *(const uint4*)(thb + r * D_ + c);
    }

    // direct global loads of this lane's B-fragments, convert in-register
    const float* xr = x + (size_t)(row0 + w * 16 + n) * D_ + quad * 8;
    const float* yr = y + (size_t)(row0 + w * 16 + n) * D_ + quad * 8;
    short8 bx[4], by[4];
    {
        float4 lx[8];
        #pragma unroll
        for (int ks = 0; ks < 4; ++ks) {
            lx[2*ks]   = *(const float4*)(xr + ks * 32);
            lx[2*ks+1] = *(const float4*)(xr + ks * 32 + 4);
        }
        #pragma unroll
        for (int ks = 0; ks < 4; ++ks) {
            short8 t;
            t[0] = (short)f2b(lx[2*ks].x);   t[1] = (short)f2b(lx[2*ks].y);
            t[2] = (short)f2b(lx[2*ks].z);   t[3] = (short)f2b(lx[2*ks].w);
            t[4] = (short)f2b(lx[2*ks+1].x); t[5] = (short)f2b(lx[2*ks+1].y);
            t[6] = (short)f2b(lx[2*ks+1].z); t[7] = (short)f2b(lx[2*ks+1].w);
            bx[ks] = t;
        }
    }
    {
        float4 ly[8];
        #pragma unroll
        for (int ks = 0; ks < 4; ++ks) {
            ly[2*ks]   = *(const float4*)(yr + ks * 32);
            ly[2*ks+1] = *(const float4*)(yr + ks * 32 + 4);
        }
        #pragma unroll
        for (int ks = 0; ks < 4; ++ks) {
            short8 t;
            t[0] = (short)f2b(ly[2*ks].x);   t[1] = (short)f2b(ly[2*ks].y);
            t[2] = (short)f2b(ly[2*ks].z);   t[3] = (short)f2b(ly[2*ks].w);
            t[4] = (short)f2b(ly[2*ks+1].x); t[5] = (short)f2b(ly[2*ks+1].y);
            t[6] = (short)f2b(ly[2*ks+1].z); t[7] = (short)f2b(ly[2*ks+1].w);
            by[ks] = t;
        }
    }
    __syncthreads();                          // theta staged

    floatx4 ay[7];                            // held y accumulators (28 VGPR)

    // ---- phase A: x projections p 0..63 ----
    #pragma unroll
    for (int pt = 0; pt < 4; ++pt) {
        floatx4 accx = {0.f, 0.f, 0.f, 0.f};
        floatx4 accy = {0.f, 0.f, 0.f, 0.f};
        #pragma unroll
        for (int ks = 0; ks < 4; ++ks) {
            short8 a = *(const short8*)(th_s + (pt * 16 + n) * 136 + ks * 32 + quad * 8);
            accx = __builtin_amdgcn_mfma_f32_16x16x32_bf16(a, bx[ks], accx, 0, 0, 0);
            accy = __builtin_amdgcn_mfma_f32_16x16x32_bf16(a, by[ks], accy, 0, 0, 0);
        }
        #pragma unroll
        for (int reg = 0; reg < 4; ++reg)
            buf[(pt * 16 + quad * 4 + reg) * 72 + w * 16 + n] = f2b(accx[reg]);
        ay[pt] = accy;
    }
    __syncthreads();
    for (int g = tid; g < 512; g += 256) {
        int p = g >> 3, c = (g & 7) << 3;
        *(uint4*)(xp + (size_t)p * BN_ + row0 + c) = *(const uint4*)(buf + p * 72 + c);
    }
    __syncthreads();

    // ---- phase B: x projections p 64..99 ----
    #pragma unroll
    for (int pt = 4; pt < 7; ++pt) {
        floatx4 accx = {0.f, 0.f, 0.f, 0.f};
        floatx4 accy = {0.f, 0.f, 0.f, 0.f};
        #pragma unroll
        for (int ks = 0; ks < 4; ++ks) {
            short8 a = *(const short8*)(th_s + (pt * 16 + n) * 136 + ks * 32 + quad * 8);
            accx = __builtin_amdgcn_mfma_f32_16x16x32_bf16(a, bx[ks], accx, 0, 0, 0);
            accy = __builtin_amdgcn_mfma_f32_16x16x32_bf16(a, by[ks], accy, 0, 0, 0);
        }
        #pragma unroll
        for (int reg = 0; reg < 4; ++reg)
            buf[((pt - 4) * 16 + quad * 4 + reg) * 72 + w * 16 + n] = f2b(accx[reg]);
        ay[pt] = accy;
    }
    __syncthreads();
    for (int g = tid; g < 288; g += 256) {    // p 64..99 (36 rows)
        int p = g >> 3, c = (g & 7) << 3;
        *(uint4*)(xp + (size_t)(64 + p) * BN_ + row0 + c) = *(const uint4*)(buf + p * 72 + c);
    }
    __syncthreads();

    // ---- phase C: y projections p 0..63 ----
    #pragma unroll
    for (int pt = 0; pt < 4; ++pt)
        #pragma unroll
        for (int reg = 0; reg < 4; ++reg)
            buf[(pt * 16 + quad * 4 + reg) * 72 + w * 16 + n] = f2b(ay[pt][reg]);
    __syncthreads();
    for (int g = tid; g < 512; g += 256) {
        int p = g >> 3, c = (g & 7) << 3;
        *(uint4*)(yp + (size_t)p * BN_ + row0 + c) = *(const uint4*)(buf + p * 72 + c);
    }
    __syncthreads();

    // ---- phase D: y projections p 64..99 ----
    #pragma unroll
    for (int pt = 4; pt < 7; ++pt)
        #pragma unroll
        for (int reg = 0; reg < 4; ++reg)
            buf[((pt - 4) * 16 + quad * 4 + reg) * 72 + w * 16 + n] = f2b(ay[pt][reg]);
    __syncthreads();
    for (int g = tid; g < 288; g += 256) {
        int p = g >> 3, c = (g & 7) << 3;
        *(uint4*)(yp + (size_t)(64 + p) * BN_ + row0 + c) = *(const uint4*)(buf + p * 72 + c);
    }
}

// ---------------------------------------------------------------------------
// Kernel 3: fused counting sort + rank + diff.  Packed histogram: y counts in
// low 16 (+1), x counts in high 16 (+0x10000); max count 16384 < 2^16 so the
// packed exclusive scan is field-independent (total 0x4000_4000, no carry).
// Proven R4 shape: 1024 thr x 16 elems, launch_bounds(1024,4) — ~100 VGPR,
// zero spill, wave-contiguous uint4 I/O.  UNCHANGED.
// ---------------------------------------------------------------------------
__device__ __forceinline__ int binof(float v) {
    int k = (int)((v + 8.0f) * 256.0f);
    return k < 0 ? 0 : (k > NBIN - 1 ? NBIN - 1 : k);
}

__device__ __forceinline__ void scan4(unsigned* hist, volatile unsigned* wsum, int t) {
    unsigned v[4], run = 0;
    #pragma unroll
    for (int i = 0; i < 4; ++i) { unsigned h = hist[t * 4 + i]; v[i] = run; run += h; }
    const int lane = t & 63, w = t >> 6;
    unsigned inc = run;
    #pragma unroll
    for (int off = 1; off < 64; off <<= 1) {
        unsigned nbr = __shfl_up(inc, off, 64);
        if (lane >= off) inc += nbr;
    }
    if (lane == 63) wsum[w] = inc;
    __syncthreads();
    if (t == 0) {
        unsigned r2 = 0;
        #pragma unroll
        for (int i = 0; i < 16; ++i) { unsigned h = wsum[i]; wsum[i] = r2; r2 += h; }
    }
    __syncthreads();
    unsigned base = wsum[w] + (inc - run);
    #pragma unroll
    for (int i = 0; i < 4; ++i) hist[t * 4 + i] = base + v[i];
}

__global__ __launch_bounds__(1024, 4) void k_sortdiff(
    const unsigned short* __restrict__ xp, const unsigned short* __restrict__ yp,
    unsigned short* __restrict__ diff) {
    __shared__ unsigned hist[NBIN];           // 16 KB (packed y|x)
    __shared__ unsigned short ysort[N_];      // 32 KB
    __shared__ unsigned wsum[16];
    const int t = threadIdx.x;
    const unsigned* ypd = (const unsigned*)(yp + (size_t)blockIdx.x * N_);
    const unsigned* xpd = (const unsigned*)(xp + (size_t)blockIdx.x * N_);
    unsigned*       dfd = (unsigned*)(diff + (size_t)blockIdx.x * N_);

    // 16 elems/thread; wave-contiguous uint4 loads (lane-adjacent 16 B)
    unsigned yw[8], xw[8];
    #pragma unroll
    for (int i = 0; i < 2; ++i) {
        uint4 a = *(const uint4*)(ypd + i * 4096 + t * 4);
        yw[4*i] = a.x; yw[4*i+1] = a.y; yw[4*i+2] = a.z; yw[4*i+3] = a.w;
        uint4 c = *(const uint4*)(xpd + i * 4096 + t * 4);
        xw[4*i] = c.x; xw[4*i+1] = c.y; xw[4*i+2] = c.z; xw[4*i+3] = c.w;
    }

    #pragma unroll
    for (int i = 0; i < 4; ++i) hist[t + i * 1024] = 0;
    __syncthreads();

    // ---- single packed count pass (returning: own field IS intra-bin idx) ----
    unsigned jy[8], jx[8];
    #pragma unroll
    for (int k = 0; k < 8; ++k) {
        unsigned j0 = atomicAdd(&hist[binof(b2f((unsigned short)(yw[k] & 0xffff)))], 1u);
        unsigned j1 = atomicAdd(&hist[binof(b2f((unsigned short)(yw[k] >> 16)))], 1u);
        jy[k] = (j0 & 0xffffu) | (j1 << 16);
        unsigned i0 = atomicAdd(&hist[binof(b2f((unsigned short)(xw[k] & 0xffff)))], 0x10000u);
        unsigned i1 = atomicAdd(&hist[binof(b2f((unsigned short)(xw[k] >> 16)))], 0x10000u);
        jx[k] = (i0 >> 16) | (i1 & 0xffff0000u);
    }
    __syncthreads();
    scan4(hist, wsum, t);                     // packed exclusive prefix, both fields
    __syncthreads();

    // scatter y into LDS (low field) and fold x rank into jx (high field)
    #pragma unroll
    for (int k = 0; k < 8; ++k) {
        unsigned short e0 = (unsigned short)(yw[k] & 0xffff);
        unsigned short e1 = (unsigned short)(yw[k] >> 16);
        ysort[(hist[binof(b2f(e0))] & 0xffffu) + (jy[k] & 0xffffu)] = e0;
        ysort[(hist[binof(b2f(e1))] & 0xffffu) + (jy[k] >> 16)]     = e1;
        unsigned r0 = (hist[binof(b2f((unsigned short)(xw[k] & 0xffff)))] >> 16) + (jx[k] & 0xffffu);
        unsigned r1 = (hist[binof(b2f((unsigned short)(xw[k] >> 16)))] >> 16) + (jx[k] >> 16);
        jx[k] = r0 | (r1 << 16);
    }
    __syncthreads();

    // gather transported y, write diff (wave-contiguous uint4 stores)
    #pragma unroll
    for (int i = 0; i < 2; ++i) {
        unsigned o[4];
        #pragma unroll
        for (int q = 0; q < 4; ++q) {
            int k = 4*i + q;
            float x0 = b2f((unsigned short)(xw[k] & 0xffff));
            float x1 = b2f((unsigned short)(xw[k] >> 16));
            unsigned short d0 = f2b(b2f(ysort[jx[k] & 0xffffu]) - x0);
            unsigned short d1 = f2b(b2f(ysort[jx[k] >> 16]) - x1);
            o[q] = (unsigned)d0 | ((unsigned)d1 << 16);
        }
        *(uint4*)(dfd + i * 4096 + t * 4) = make_uint4(o[0], o[1], o[2], o[3]);
    }
}

// ---------------------------------------------------------------------------
// Kernel 4: combine via bf16 MFMA, transpose fused into the LDS stage.
// R8: EXACT-OCCUPANCY variant.  thbT now staged in TWO HALVES ([64][136] =
// 17.4 KB): pass0 computes out d 0..63, barrier, restage rows 64..127, pass1
// computes d 64..127.  LDS 52.2 -> 34.8 KB -> 4 blocks/CU -> grid 1024 =
// 1024 slots -> 1.0 rounds, 16 waves/CU (was 3 blocks / 1.33 rounds / 12).
// Lp transpose tile unchanged (R4-proven); A-frags held in regs across both
// passes.  launch_bounds(256,4): cap 128 VGPR, live ~80.
// ---------------------------------------------------------------------------
__global__ __launch_bounds__(256, 4) void k_comb(
    const float* __restrict__ x, const unsigned short* __restrict__ diff,
    const unsigned short* __restrict__ thbT, float* __restrict__ out) {
    __shared__ unsigned short ths[64 * 136];  // 17,408 B (half of thbT)
    __shared__ unsigned Lp[64 * 68];          // 17,408 B  [k2][row] pair-packed
    const int tid  = threadIdx.x;
    const int w    = tid >> 6;                // wave -> rows w*16..+15
    const int lane = tid & 63;
    const int n16  = lane & 15;
    const int quad = lane >> 4;
    const int row0 = blockIdx.x * 64;

    for (int g = tid; g < 1024; g += 256) {   // thbT rows 0..63 -> LDS
        int r = g >> 4, c = (g & 15) << 3;
        *(uint4*)(ths + r * 136 + c) = *(const uint4*)(thbT + r * KPAD + c);
    }
    for (int g = tid; g < 952; g += 256) Lp[50 * 68 + g] = 0;   // k2=50..63 pad
    for (int g = tid; g < 400; g += 256) {    // 50 p-pairs x 8 row-groups
        int p2 = g >> 3, rg = (g & 7) << 3;
        uint4 a = *(const uint4*)(diff + (size_t)(2 * p2) * BN_ + row0 + rg);
        uint4 b = *(const uint4*)(diff + (size_t)(2 * p2 + 1) * BN_ + row0 + rg);
        unsigned* dst = Lp + p2 * 68 + rg;
        dst[0] = (a.x & 0xffffu) | (b.x << 16);
        dst[1] = (a.x >> 16)     | (b.x & 0xffff0000u);
        dst[2] = (a.y & 0xffffu) | (b.y << 16);
        dst[3] = (a.y >> 16)     | (b.y & 0xffff0000u);
        dst[4] = (a.z & 0xffffu) | (b.z << 16);
        dst[5] = (a.z >> 16)     | (b.z & 0xffff0000u);
        dst[6] = (a.w & 0xffffu) | (b.w << 16);
        dst[7] = (a.w >> 16)     | (b.w & 0xffff0000u);
    }
    __syncthreads();

    // A-frags: lane row r = w*16+n16, k = ks*32 + quad*8 + 0..7 (held both passes)
    const int r = w * 16 + n16;
    short8 af[4];
    #pragma unroll
    for (int ks = 0; ks < 4; ++ks) {
        union { unsigned u[4]; short8 v; } tu;
        #pragma unroll
        for (int m = 0; m < 4; ++m)
            tu.u[m] = Lp[(ks * 16 + quad * 4 + m) * 68 + r];
        af[ks] = tu.v;
    }

    const float invP = 1.0f / (float)P_;
    const size_t rbase = (size_t)(row0 + w * 16 + quad * 4) * D_ + n16;

    // ---- pass 0: d 0..63 ----
    #pragma unroll
    for (int nt = 0; nt < 4; ++nt) {
        floatx4 acc = {0.f, 0.f, 0.f, 0.f};
        #pragma unroll
        for (int ks = 0; ks < 4; ++ks) {
            short8 b = *(const short8*)(ths + (nt * 16 + n16) * 136 + ks * 32 + quad * 8);
            acc = __builtin_amdgcn_mfma_f32_16x16x32_bf16(af[ks], b, acc, 0, 0, 0);
        }
        #pragma unroll
        for (int reg = 0; reg < 4; ++reg) {
            size_t o = rbase + (size_t)reg * D_ + nt * 16;
            out[o] = fmaf(acc[reg], invP, x[o]);
        }
    }
    __syncthreads();                          // all waves done with ths half0

    for (int g = tid; g < 1024; g += 256) {   // thbT rows 64..127 -> LDS
        int r2 = g >> 4, c = (g & 15) << 3;
        *(uint4*)(ths + r2 * 136 + c) = *(const uint4*)(thbT + (size_t)(64 + r2) * KPAD + c);
    }
    __syncthreads();

    // ---- pass 1: d 64..127 ----
    #pragma unroll
    for (int nt = 0; nt < 4; ++nt) {
        floatx4 acc = {0.f, 0.f, 0.f, 0.f};
        #pragma unroll
        for (int ks = 0; ks < 4; ++ks) {
            short8 b = *(const short8*)(ths + (nt * 16 + n16) * 136 + ks * 32 + quad * 8);
            acc = __builtin_amdgcn_mfma_f32_16x16x32_bf16(af[ks], b, acc, 0, 0, 0);
        }
        #pragma unroll
        for (int reg = 0; reg < 4; ++reg) {
            size_t o = rbase + (size_t)reg * D_ + (64 + nt * 16);
            out[o] = fmaf(acc[reg], invP, x[o]);
        }
    }
}

// ---------------------------------------------------------------------------
// Workspace (bytes): thb[0, 32KB) thbT[32KB, 64KB) xp[64KB, +13.1MB)
// yp(+13.1MB) => ~26.3 MB. diff overwrites xp in place.
// ---------------------------------------------------------------------------
extern "C" void kernel_launch(void* const* d_in, const int* in_sizes, int n_in,
                              void* d_out, int out_size, void* d_ws, size_t ws_size,
                              hipStream_t stream) {
    const float* x  = (const float*)d_in[0];
    const float* y  = (const float*)d_in[1];
    const float* th = (const float*)d_in[2];
    float* out = (float*)d_out;
    char*  wsb = (char*)d_ws;

    unsigned short* thb  = (unsigned short*)wsb;
    unsigned short* thbT = (unsigned short*)(wsb + 32768);
    unsigned short* xpb  = (unsigned short*)(wsb + 65536);
    unsigned short* ypb  = xpb + PBN_;

    k_norm<<<128, 128, 0, stream>>>(th, thb, thbT);
    k_proj<<<BN_ / 64, 256, 0, stream>>>(x, y, thb, xpb, ypb);
    k_sortdiff<<<P_ * B_, 1024, 0, stream>>>(xpb, ypb, xpb);
    k_comb<<<BN_ / 64, 256, 0, stream>>>(x, xpb, thbT, out);
}

// Round 9
// 138.266 us; speedup vs baseline: 1.1758x; 1.0175x over previous
//
#include <hip/hip_runtime.h>
#include <hip/hip_bf16.h>

#define B_    4
#define N_    16384
#define D_    128
#define P_    100
#define BN_   65536      // B_*N_
#define PBN_  6553600    // P_*BN_
#define PPAD  112        // P padded to 7*16 MFMA p-tiles (k_proj)
#define KPAD  128        // P padded to 128 for k_comb's K dimension
#define NBIN  4096

typedef __attribute__((ext_vector_type(8))) short short8;   // 8 bf16 = 4 VGPR
typedef __attribute__((ext_vector_type(4))) float floatx4;  // MFMA C/D

// bf16 <-> f32 via raw bits (RNE; inputs are finite)
__device__ __forceinline__ unsigned short f2b(float f) {
    unsigned u = __float_as_uint(f);
    return (unsigned short)((u + 0x7FFFu + ((u >> 16) & 1u)) >> 16);
}
__device__ __forceinline__ float b2f(unsigned short h) {
    return __uint_as_float(((unsigned)h) << 16);
}

// ---------------------------------------------------------------------------
// Kernel 1: theta normalization -> thb[p][d] (k_proj A-operand, rows >=100
// zero) and thbT[d][p] (k_comb B-operand, cols >=100 zero; NaN-safe K-pad).
// ---------------------------------------------------------------------------
__global__ void k_norm(const float* __restrict__ th,
                       unsigned short* __restrict__ thb,
                       unsigned short* __restrict__ thbT) {
    int p = blockIdx.x;       // 0..127
    int d = threadIdx.x;      // 0..127
    float v = 0.f;
    if (p < P_) v = th[p * D_ + d];
    float s = v * v;
    #pragma unroll
    for (int o = 32; o > 0; o >>= 1) s += __shfl_down(s, o, 64);
    __shared__ float red[2];
    if ((d & 63) == 0) red[d >> 6] = s;
    __syncthreads();
    float norm = fmaxf(sqrtf(red[0] + red[1]), 1e-12f);
    unsigned short r = f2b(v / norm);       // p>=100 -> 0/1e-12 = +0
    if (p < PPAD) thb[p * D_ + d] = r;
    thbT[d * KPAD + p] = r;
}

// ---------------------------------------------------------------------------
// Kernel 2: projections via bf16 MFMA 16x16x32.  (R8-proven exact-occupancy
// version: [64][72] shared buf, 4 store phases, ay[7] held in VGPRs,
// LDS 39.7 KB -> 4 blocks/CU, 1.0 rounds.)  UNCHANGED.
// ---------------------------------------------------------------------------
__global__ __launch_bounds__(256, 4) void k_proj(
    const float* __restrict__ x, const float* __restrict__ y,
    const unsigned short* __restrict__ thb,
    unsigned short* __restrict__ xp, unsigned short* __restrict__ yp) {
    __shared__ unsigned short th_s[15232];    // [112][136] 30,464 B
    __shared__ unsigned short buf[4608];      // [64][72]    9,216 B
    const int tid  = threadIdx.x;
    const int w    = tid >> 6;                // wave 0..3 -> rows w*16..+15
    const int lane = tid & 63;
    const int n    = lane & 15;
    const int quad = lane >> 4;
    const int row0 = blockIdx.x * 64;

    for (int g = tid; g < 1792; g += 256) {   // theta 112x128 bf16 -> LDS
        int r = g >> 4, c = (g & 15) << 3;
        *(uint4*)(th_s + r * 136 + c) = *(const uint4*)(thb + r * D_ + c);
    }

    // direct global loads of this lane's B-fragments, convert in-register
    const float* xr = x + (size_t)(row0 + w * 16 + n) * D_ + quad * 8;
    const float* yr = y + (size_t)(row0 + w * 16 + n) * D_ + quad * 8;
    short8 bx[4], by[4];
    {
        float4 lx[8];
        #pragma unroll
        for (int ks = 0; ks < 4; ++ks) {
            lx[2*ks]   = *(const float4*)(xr + ks * 32);
            lx[2*ks+1] = *(const float4*)(xr + ks * 32 + 4);
        }
        #pragma unroll
        for (int ks = 0; ks < 4; ++ks) {
            short8 t;
            t[0] = (short)f2b(lx[2*ks].x);   t[1] = (short)f2b(lx[2*ks].y);
            t[2] = (short)f2b(lx[2*ks].z);   t[3] = (short)f2b(lx[2*ks].w);
            t[4] = (short)f2b(lx[2*ks+1].x); t[5] = (short)f2b(lx[2*ks+1].y);
            t[6] = (short)f2b(lx[2*ks+1].z); t[7] = (short)f2b(lx[2*ks+1].w);
            bx[ks] = t;
        }
    }
    {
        float4 ly[8];
        #pragma unroll
        for (int ks = 0; ks < 4; ++ks) {
            ly[2*ks]   = *(const float4*)(yr + ks * 32);
            ly[2*ks+1] = *(const float4*)(yr + ks * 32 + 4);
        }
        #pragma unroll
        for (int ks = 0; ks < 4; ++ks) {
            short8 t;
            t[0] = (short)f2b(ly[2*ks].x);   t[1] = (short)f2b(ly[2*ks].y);
            t[2] = (short)f2b(ly[2*ks].z);   t[3] = (short)f2b(ly[2*ks].w);
            t[4] = (short)f2b(ly[2*ks+1].x); t[5] = (short)f2b(ly[2*ks+1].y);
            t[6] = (short)f2b(ly[2*ks+1].z); t[7] = (short)f2b(ly[2*ks+1].w);
            by[ks] = t;
        }
    }
    __syncthreads();                          // theta staged

    floatx4 ay[7];                            // held y accumulators (28 VGPR)

    // ---- phase A: x projections p 0..63 ----
    #pragma unroll
    for (int pt = 0; pt < 4; ++pt) {
        floatx4 accx = {0.f, 0.f, 0.f, 0.f};
        floatx4 accy = {0.f, 0.f, 0.f, 0.f};
        #pragma unroll
        for (int ks = 0; ks < 4; ++ks) {
            short8 a = *(const short8*)(th_s + (pt * 16 + n) * 136 + ks * 32 + quad * 8);
            accx = __builtin_amdgcn_mfma_f32_16x16x32_bf16(a, bx[ks], accx, 0, 0, 0);
            accy = __builtin_amdgcn_mfma_f32_16x16x32_bf16(a, by[ks], accy, 0, 0, 0);
        }
        #pragma unroll
        for (int reg = 0; reg < 4; ++reg)
            buf[(pt * 16 + quad * 4 + reg) * 72 + w * 16 + n] = f2b(accx[reg]);
        ay[pt] = accy;
    }
    __syncthreads();
    for (int g = tid; g < 512; g += 256) {
        int p = g >> 3, c = (g & 7) << 3;
        *(uint4*)(xp + (size_t)p * BN_ + row0 + c) = *(const uint4*)(buf + p * 72 + c);
    }
    __syncthreads();

    // ---- phase B: x projections p 64..99 ----
    #pragma unroll
    for (int pt = 4; pt < 7; ++pt) {
        floatx4 accx = {0.f, 0.f, 0.f, 0.f};
        floatx4 accy = {0.f, 0.f, 0.f, 0.f};
        #pragma unroll
        for (int ks = 0; ks < 4; ++ks) {
            short8 a = *(const short8*)(th_s + (pt * 16 + n) * 136 + ks * 32 + quad * 8);
            accx = __builtin_amdgcn_mfma_f32_16x16x32_bf16(a, bx[ks], accx, 0, 0, 0);
            accy = __builtin_amdgcn_mfma_f32_16x16x32_bf16(a, by[ks], accy, 0, 0, 0);
        }
        #pragma unroll
        for (int reg = 0; reg < 4; ++reg)
            buf[((pt - 4) * 16 + quad * 4 + reg) * 72 + w * 16 + n] = f2b(accx[reg]);
        ay[pt] = accy;
    }
    __syncthreads();
    for (int g = tid; g < 288; g += 256) {    // p 64..99 (36 rows)
        int p = g >> 3, c = (g & 7) << 3;
        *(uint4*)(xp + (size_t)(64 + p) * BN_ + row0 + c) = *(const uint4*)(buf + p * 72 + c);
    }
    __syncthreads();

    // ---- phase C: y projections p 0..63 ----
    #pragma unroll
    for (int pt = 0; pt < 4; ++pt)
        #pragma unroll
        for (int reg = 0; reg < 4; ++reg)
            buf[(pt * 16 + quad * 4 + reg) * 72 + w * 16 + n] = f2b(ay[pt][reg]);
    __syncthreads();
    for (int g = tid; g < 512; g += 256) {
        int p = g >> 3, c = (g & 7) << 3;
        *(uint4*)(yp + (size_t)p * BN_ + row0 + c) = *(const uint4*)(buf + p * 72 + c);
    }
    __syncthreads();

    // ---- phase D: y projections p 64..99 ----
    #pragma unroll
    for (int pt = 4; pt < 7; ++pt)
        #pragma unroll
        for (int reg = 0; reg < 4; ++reg)
            buf[((pt - 4) * 16 + quad * 4 + reg) * 72 + w * 16 + n] = f2b(ay[pt][reg]);
    __syncthreads();
    for (int g = tid; g < 288; g += 256) {
        int p = g >> 3, c = (g & 7) << 3;
        *(uint4*)(yp + (size_t)(64 + p) * BN_ + row0 + c) = *(const uint4*)(buf + p * 72 + c);
    }
}

// ---------------------------------------------------------------------------
// Kernel 3: fused counting sort + rank + diff.
// R9: ONE-ROUND variant.  At ~100 VGPR a 1024-thr block = 16 waves/CU =
// 1 block/CU -> grid 400 runs TWO rounds (2nd only 56% full) -> ~21 us.
// Going to 2 blocks/CU needs VGPR <= 64 (launch_bounds(1024,8)) — R1's spill
// config.  Fix is algorithmic: do NOT keep yw/xw live across the scan.
// Count pass consumes each uint4 transiently, keeping ONLY the atomic
// returns (jy[8]+jx[8] = 16 regs).  After the scan, RELOAD yp/xp from
// global (pure L2 hits — 26 MB just written, L2 = 32 MB; +64 B/thread) and
// recompute bins for scatter/gather.  Live across scan ~45 VGPR < 64.
// 400 blocks at 2/CU = one round.  Packed hist (y lo16 / x hi16) unchanged.
// ---------------------------------------------------------------------------
__device__ __forceinline__ int binof(float v) {
    int k = (int)((v + 8.0f) * 256.0f);
    return k < 0 ? 0 : (k > NBIN - 1 ? NBIN - 1 : k);
}

__device__ __forceinline__ void scan4(unsigned* hist, volatile unsigned* wsum, int t) {
    unsigned v[4], run = 0;
    #pragma unroll
    for (int i = 0; i < 4; ++i) { unsigned h = hist[t * 4 + i]; v[i] = run; run += h; }
    const int lane = t & 63, w = t >> 6;
    unsigned inc = run;
    #pragma unroll
    for (int off = 1; off < 64; off <<= 1) {
        unsigned nbr = __shfl_up(inc, off, 64);
        if (lane >= off) inc += nbr;
    }
    if (lane == 63) wsum[w] = inc;
    __syncthreads();
    if (t == 0) {
        unsigned r2 = 0;
        #pragma unroll
        for (int i = 0; i < 16; ++i) { unsigned h = wsum[i]; wsum[i] = r2; r2 += h; }
    }
    __syncthreads();
    unsigned base = wsum[w] + (inc - run);
    #pragma unroll
    for (int i = 0; i < 4; ++i) hist[t * 4 + i] = base + v[i];
}

__global__ __launch_bounds__(1024, 8) void k_sortdiff(
    const unsigned short* __restrict__ xp, const unsigned short* __restrict__ yp,
    unsigned short* __restrict__ diff) {
    __shared__ unsigned hist[NBIN];           // 16 KB (packed y|x)
    __shared__ unsigned short ysort[N_];      // 32 KB
    __shared__ unsigned wsum[16];
    const int t = threadIdx.x;
    const unsigned* ypd = (const unsigned*)(yp + (size_t)blockIdx.x * N_);
    const unsigned* xpd = (const unsigned*)(xp + (size_t)blockIdx.x * N_);
    unsigned*       dfd = (unsigned*)(diff + (size_t)blockIdx.x * N_);

    #pragma unroll
    for (int i = 0; i < 4; ++i) hist[t + i * 1024] = 0;
    __syncthreads();

    // ---- packed count pass: stream loads, keep ONLY atomic returns ----
    unsigned jy[8], jx[8];
    #pragma unroll
    for (int i = 0; i < 2; ++i) {
        uint4 a = *(const uint4*)(ypd + i * 4096 + t * 4);
        unsigned aw0 = a.x, aw1 = a.y, aw2 = a.z, aw3 = a.w;
        unsigned aws[4] = {aw0, aw1, aw2, aw3};
        #pragma unroll
        for (int q = 0; q < 4; ++q) {
            unsigned j0 = atomicAdd(&hist[binof(b2f((unsigned short)(aws[q] & 0xffff)))], 1u);
            unsigned j1 = atomicAdd(&hist[binof(b2f((unsigned short)(aws[q] >> 16)))], 1u);
            jy[4*i + q] = (j0 & 0xffffu) | (j1 << 16);
        }
    }
    #pragma unroll
    for (int i = 0; i < 2; ++i) {
        uint4 c = *(const uint4*)(xpd + i * 4096 + t * 4);
        unsigned cw0 = c.x, cw1 = c.y, cw2 = c.z, cw3 = c.w;
        unsigned cws[4] = {cw0, cw1, cw2, cw3};
        #pragma unroll
        for (int q = 0; q < 4; ++q) {
            unsigned i0 = atomicAdd(&hist[binof(b2f((unsigned short)(cws[q] & 0xffff)))], 0x10000u);
            unsigned i1 = atomicAdd(&hist[binof(b2f((unsigned short)(cws[q] >> 16)))], 0x10000u);
            jx[4*i + q] = (i0 >> 16) | (i1 & 0xffff0000u);
        }
    }
    __syncthreads();
    scan4(hist, wsum, t);                     // packed exclusive prefix, both fields
    __syncthreads();

    // ---- scatter y into LDS (reload y from L2, recompute bins) ----
    #pragma unroll
    for (int i = 0; i < 2; ++i) {
        uint4 a = *(const uint4*)(ypd + i * 4096 + t * 4);
        unsigned aws[4] = {a.x, a.y, a.z, a.w};
        #pragma unroll
        for (int q = 0; q < 4; ++q) {
            int k = 4*i + q;
            unsigned short e0 = (unsigned short)(aws[q] & 0xffff);
            unsigned short e1 = (unsigned short)(aws[q] >> 16);
            ysort[(hist[binof(b2f(e0))] & 0xffffu) + (jy[k] & 0xffffu)] = e0;
            ysort[(hist[binof(b2f(e1))] & 0xffffu) + (jy[k] >> 16)]     = e1;
        }
    }
    __syncthreads();

    // ---- gather transported y + diff (reload x from L2) ----
    #pragma unroll
    for (int i = 0; i < 2; ++i) {
        uint4 c = *(const uint4*)(xpd + i * 4096 + t * 4);
        unsigned cws[4] = {c.x, c.y, c.z, c.w};
        unsigned o[4];
        #pragma unroll
        for (int q = 0; q < 4; ++q) {
            int k = 4*i + q;
            float x0 = b2f((unsigned short)(cws[q] & 0xffff));
            float x1 = b2f((unsigned short)(cws[q] >> 16));
            unsigned r0 = (hist[binof(x0)] >> 16) + (jx[k] & 0xffffu);
            unsigned r1 = (hist[binof(x1)] >> 16) + (jx[k] >> 16);
            unsigned short d0 = f2b(b2f(ysort[r0]) - x0);
            unsigned short d1 = f2b(b2f(ysort[r1]) - x1);
            o[q] = (unsigned)d0 | ((unsigned)d1 << 16);
        }
        *(uint4*)(dfd + i * 4096 + t * 4) = make_uint4(o[0], o[1], o[2], o[3]);
    }
}

// ---------------------------------------------------------------------------
// Kernel 4: combine via bf16 MFMA, transpose fused into the LDS stage.
// (R8-proven exact-occupancy version: thbT staged in two halves, LDS 34.8 KB
// -> 4 blocks/CU, 1.0 rounds.)  UNCHANGED.
// ---------------------------------------------------------------------------
__global__ __launch_bounds__(256, 4) void k_comb(
    const float* __restrict__ x, const unsigned short* __restrict__ diff,
    const unsigned short* __restrict__ thbT, float* __restrict__ out) {
    __shared__ unsigned short ths[64 * 136];  // 17,408 B (half of thbT)
    __shared__ unsigned Lp[64 * 68];          // 17,408 B  [k2][row] pair-packed
    const int tid  = threadIdx.x;
    const int w    = tid >> 6;                // wave -> rows w*16..+15
    const int lane = tid & 63;
    const int n16  = lane & 15;
    const int quad = lane >> 4;
    const int row0 = blockIdx.x * 64;

    for (int g = tid; g < 1024; g += 256) {   // thbT rows 0..63 -> LDS
        int r = g >> 4, c = (g & 15) << 3;
        *(uint4*)(ths + r * 136 + c) = *(const uint4*)(thbT + r * KPAD + c);
    }
    for (int g = tid; g < 952; g += 256) Lp[50 * 68 + g] = 0;   // k2=50..63 pad
    for (int g = tid; g < 400; g += 256) {    // 50 p-pairs x 8 row-groups
        int p2 = g >> 3, rg = (g & 7) << 3;
        uint4 a = *(const uint4*)(diff + (size_t)(2 * p2) * BN_ + row0 + rg);
        uint4 b = *(const uint4*)(diff + (size_t)(2 * p2 + 1) * BN_ + row0 + rg);
        unsigned* dst = Lp + p2 * 68 + rg;
        dst[0] = (a.x & 0xffffu) | (b.x << 16);
        dst[1] = (a.x >> 16)     | (b.x & 0xffff0000u);
        dst[2] = (a.y & 0xffffu) | (b.y << 16);
        dst[3] = (a.y >> 16)     | (b.y & 0xffff0000u);
        dst[4] = (a.z & 0xffffu) | (b.z << 16);
        dst[5] = (a.z >> 16)     | (b.z & 0xffff0000u);
        dst[6] = (a.w & 0xffffu) | (b.w << 16);
        dst[7] = (a.w >> 16)     | (b.w & 0xffff0000u);
    }
    __syncthreads();

    // A-frags: lane row r = w*16+n16, k = ks*32 + quad*8 + 0..7 (held both passes)
    const int r = w * 16 + n16;
    short8 af[4];
    #pragma unroll
    for (int ks = 0; ks < 4; ++ks) {
        union { unsigned u[4]; short8 v; } tu;
        #pragma unroll
        for (int m = 0; m < 4; ++m)
            tu.u[m] = Lp[(ks * 16 + quad * 4 + m) * 68 + r];
        af[ks] = tu.v;
    }

    const float invP = 1.0f / (float)P_;
    const size_t rbase = (size_t)(row0 + w * 16 + quad * 4) * D_ + n16;

    // ---- pass 0: d 0..63 ----
    #pragma unroll
    for (int nt = 0; nt < 4; ++nt) {
        floatx4 acc = {0.f, 0.f, 0.f, 0.f};
        #pragma unroll
        for (int ks = 0; ks < 4; ++ks) {
            short8 b = *(const short8*)(ths + (nt * 16 + n16) * 136 + ks * 32 + quad * 8);
            acc = __builtin_amdgcn_mfma_f32_16x16x32_bf16(af[ks], b, acc, 0, 0, 0);
        }
        #pragma unroll
        for (int reg = 0; reg < 4; ++reg) {
            size_t o = rbase + (size_t)reg * D_ + nt * 16;
            out[o] = fmaf(acc[reg], invP, x[o]);
        }
    }
    __syncthreads();                          // all waves done with ths half0

    for (int g = tid; g < 1024; g += 256) {   // thbT rows 64..127 -> LDS
        int r2 = g >> 4, c = (g & 15) << 3;
        *(uint4*)(ths + r2 * 136 + c) = *(const uint4*)(thbT + (size_t)(64 + r2) * KPAD + c);
    }
    __syncthreads();

    // ---- pass 1: d 64..127 ----
    #pragma unroll
    for (int nt = 0; nt < 4; ++nt) {
        floatx4 acc = {0.f, 0.f, 0.f, 0.f};
        #pragma unroll
        for (int ks = 0; ks < 4; ++ks) {
            short8 b = *(const short8*)(ths + (nt * 16 + n16) * 136 + ks * 32 + quad * 8);
            acc = __builtin_amdgcn_mfma_f32_16x16x32_bf16(af[ks], b, acc, 0, 0, 0);
        }
        #pragma unroll
        for (int reg = 0; reg < 4; ++reg) {
            size_t o = rbase + (size_t)reg * D_ + (64 + nt * 16);
            out[o] = fmaf(acc[reg], invP, x[o]);
        }
    }
}

// ---------------------------------------------------------------------------
// Workspace (bytes): thb[0, 32KB) thbT[32KB, 64KB) xp[64KB, +13.1MB)
// yp(+13.1MB) => ~26.3 MB. diff overwrites xp in place.
// ---------------------------------------------------------------------------
extern "C" void kernel_launch(void* const* d_in, const int* in_sizes, int n_in,
                              void* d_out, int out_size, void* d_ws, size_t ws_size,
                              hipStream_t stream) {
    const float* x  = (const float*)d_in[0];
    const float* y  = (const float*)d_in[1];
    const float* th = (const float*)d_in[2];
    float* out = (float*)d_out;
    char*  wsb = (char*)d_ws;

    unsigned short* thb  = (unsigned short*)wsb;
    unsigned short* thbT = (unsigned short*)(wsb + 32768);
    unsigned short* xpb  = (unsigned short*)(wsb + 65536);
    unsigned short* ypb  = xpb + PBN_;

    k_norm<<<128, 128, 0, stream>>>(th, thb, thbT);
    k_proj<<<BN_ / 64, 256, 0, stream>>>(x, y, thb, xpb, ypb);
    k_sortdiff<<<P_ * B_, 1024, 0, stream>>>(xpb, ypb, xpb);
    k_comb<<<BN_ / 64, 256, 0, stream>>>(x, xpb, thbT, out);
}